// Round 1
// baseline (616.033 us; speedup 1.0000x reference)
//
#include <hip/hip_runtime.h>
#include <cmath>

using f16   = _Float16;
using f16x4 = __attribute__((ext_vector_type(4))) _Float16;
using f16x8 = __attribute__((ext_vector_type(8))) _Float16;
using f32x4 = __attribute__((ext_vector_type(4))) float;

#define DEV __device__ __forceinline__

// ---- constants ----
constexpr int Bb  = 8;
constexpr int Nn  = 1024;
constexpr int DIM = 1024;
constexpr int Hh  = 16;
constexpr int DH  = 64;
constexpr int EQKV = 3072;   // q(1024) | k(1024) | v(1024)

DEV void async16(const f16* g, f16* l) {
  __builtin_amdgcn_global_load_lds(
      (const __attribute__((address_space(1))) void*)g,
      (__attribute__((address_space(3))) void*)l, 16, 0, 0);
}

DEV float softplusf(float x) {
  // stable: max(x,0) + log1p(exp(-|x|))
  return fmaxf(x, 0.f) + log1pf(__expf(-fabsf(x)));
}

// ---------------- transpose + fp32->fp16 convert: dst[c][r] = src[r][c] ----------------
__global__ __launch_bounds__(256) void transpose_cvt(const float* __restrict__ src,
                                                     f16* __restrict__ dst,
                                                     int rows, int cols) {
  __shared__ float tile[32][33];
  int t = threadIdx.x, tx = t & 31, ty = t >> 5;
  int c0 = blockIdx.x * 32, r0 = blockIdx.y * 32;
#pragma unroll
  for (int j = 0; j < 32; j += 8)
    tile[ty + j][tx] = src[(size_t)(r0 + ty + j) * cols + c0 + tx];
  __syncthreads();
#pragma unroll
  for (int j = 0; j < 32; j += 8)
    dst[(size_t)(c0 + ty + j) * rows + r0 + tx] = (f16)tile[tx][ty + j];
}

// ---------------- LayerNorm (fp32 in, fp16 out), one block per token row ----------------
__global__ __launch_bounds__(256) void ln_kernel(const float* __restrict__ x,
                                                 const float* __restrict__ gamma,
                                                 const float* __restrict__ beta,
                                                 f16* __restrict__ xn) {
  int row = blockIdx.x;
  int t = threadIdx.x;
  const float4* xr = (const float4*)(x + (size_t)row * DIM);
  float4 v = xr[t];
  float s  = v.x + v.y + v.z + v.w;
  float s2 = v.x * v.x + v.y * v.y + v.z * v.z + v.w * v.w;
#pragma unroll
  for (int off = 32; off; off >>= 1) {
    s  += __shfl_xor(s,  off, 64);
    s2 += __shfl_xor(s2, off, 64);
  }
  __shared__ float red[8];
  int wv = t >> 6, lane = t & 63;
  if (lane == 0) { red[wv] = s; red[4 + wv] = s2; }
  __syncthreads();
  s  = red[0] + red[1] + red[2] + red[3];
  s2 = red[4] + red[5] + red[6] + red[7];
  float mu  = s * (1.f / DIM);
  float var = s2 * (1.f / DIM) - mu * mu;
  float rs  = rsqrtf(var + 1e-5f);
  float4 g = ((const float4*)gamma)[t];
  float4 bb = ((const float4*)beta)[t];
  f16x4 o;
  o[0] = (f16)((v.x - mu) * rs * g.x + bb.x);
  o[1] = (f16)((v.y - mu) * rs * g.y + bb.y);
  o[2] = (f16)((v.z - mu) * rs * g.z + bb.z);
  o[3] = (f16)((v.w - mu) * rs * g.w + bb.w);
  ((f16x4*)(xn + (size_t)row * DIM))[t] = o;
}

// ---------------- m97-style GEMM: C[M,E] = A[M,K] * Bt[E,K]^T ----------------
// 128x128 tile, BK=32, 4 waves (2x2 of 64x64), global_load_lds(16B) staging,
// XOR swizzle (colg ^ ((row>>1)&3)) -> 2-way LDS conflicts only (free).
template <bool FP32OUT>
__global__ __launch_bounds__(256) void gemm_bt(const f16* __restrict__ A,
                                               const f16* __restrict__ Bt,
                                               void* __restrict__ Cv,
                                               const float* __restrict__ bias,
                                               int M, int K, int E) {
  __shared__ f16 lA[128 * 32];
  __shared__ f16 lB[128 * 32];
  int tid  = threadIdx.x;
  int lane = tid & 63;
  int wv   = __builtin_amdgcn_readfirstlane(tid >> 6);
  int nbe  = E >> 7;
  int bm = blockIdx.x / nbe, be = blockIdx.x % nbe;
  size_t m0 = (size_t)bm * 128, e0 = (size_t)be * 128;
  int wm = (wv & 1) * 64, we = (wv >> 1) * 64;
  int lm = lane & 15, q = lane >> 4;

  f32x4 acc[4][4] = {};

  // precompute staging geometry: slot s = r*256 + tid
  int row_s[2], cg_s[2];
#pragma unroll
  for (int r = 0; r < 2; ++r) {
    int s = r * 256 + tid;
    row_s[r] = s >> 2;
    cg_s[r]  = (s & 3) ^ ((row_s[r] >> 1) & 3);
  }
  // LDS frag addresses (iteration-invariant)
  const f16* pa[4];
  const f16* pb[4];
#pragma unroll
  for (int i = 0; i < 4; ++i) {
    int ra = wm + i * 16 + lm;
    pa[i] = lA + ra * 32 + (q ^ ((ra >> 1) & 3)) * 8;
    int rb = we + i * 16 + lm;
    pb[i] = lB + rb * 32 + (q ^ ((rb >> 1) & 3)) * 8;
  }

  for (int k0 = 0; k0 < K; k0 += 32) {
#pragma unroll
    for (int r = 0; r < 2; ++r) {
      const f16* ga = A  + (m0 + row_s[r]) * K + k0 + cg_s[r] * 8;
      const f16* gb = Bt + (e0 + row_s[r]) * K + k0 + cg_s[r] * 8;
      f16* la = lA + (r * 256 + wv * 64) * 8;
      f16* lb = lB + (r * 256 + wv * 64) * 8;
      async16(ga, la);
      async16(gb, lb);
    }
    __syncthreads();
    f16x8 af[4], bf[4];
#pragma unroll
    for (int i = 0; i < 4; ++i) {
      af[i] = *(const f16x8*)pa[i];
      bf[i] = *(const f16x8*)pb[i];
    }
#pragma unroll
    for (int i = 0; i < 4; ++i)
#pragma unroll
      for (int j = 0; j < 4; ++j)
        acc[i][j] = __builtin_amdgcn_mfma_f32_16x16x32_f16(af[i], bf[j], acc[i][j], 0, 0, 0);
    __syncthreads();
  }

  // epilogue: C row = q*4+g, col = lm
#pragma unroll
  for (int i = 0; i < 4; ++i) {
    size_t mbase = m0 + wm + i * 16 + q * 4;
#pragma unroll
    for (int j = 0; j < 4; ++j) {
      size_t e = e0 + we + j * 16 + lm;
#pragma unroll
      for (int g = 0; g < 4; ++g) {
        float val = acc[i][j][g];
        if (FP32OUT)
          ((float*)Cv)[(mbase + g) * (size_t)E + e] = val + bias[e];
        else
          ((f16*)Cv)[(mbase + g) * (size_t)E + e] = (f16)val;
      }
    }
  }
}

// ---------------- fused polar attention ----------------
// block = (b, h, 128-row q-tile); 4 waves, wave owns 32 q-rows.
// K-tiles of 64 keys; QK^T and PV via 16x16x32 f16 MFMA; online softmax.
constexpr int KPS = 136;  // kp row stride (halfs), 128+8 pad
constexpr int VTS = 72;   // vT row stride, 64+8 pad
__global__ __launch_bounds__(256) void attn_kernel(const f16* __restrict__ qkv,
                                                   const float* __restrict__ freqs,
                                                   const float* __restrict__ fbias,
                                                   f16* __restrict__ attout) {
  __shared__ f16 smem[64 * KPS + 64 * VTS + 128 * KPS];  // 61440 B
  f16* sKP = smem;                       // [64 keys][136]
  f16* sVT = smem + 64 * KPS;            // [64 d][72]
  f16* sQP = smem + 64 * KPS + 64 * VTS; // [128][136]; later wave-private P [32][72]

  int tid = threadIdx.x, lane = tid & 63, wv = tid >> 6;
  int lm = lane & 15, q = lane >> 4;
  int bx = blockIdx.x;
  int qt = bx & 7, h = (bx >> 3) & 15, b = bx >> 7;
  const size_t tok0 = (size_t)b * Nn;

  // ---- stage polar Q tile (scale folded in) ----
  constexpr float kScale = 0.125f;  // DH^-0.5
#pragma unroll 4
  for (int it = 0; it < 32; ++it) {
    int idx = tid + it * 256;         // 0..8191
    int r = idx >> 6, d = idx & 63;
    int n = qt * 128 + r;
    float qv = (float)qkv[(tok0 + n) * EQKV + h * 64 + d];
    float sp = softplusf(qv) * kScale;
    float f = freqs[n * 64 + d];
    sQP[r * KPS + d]      = (f16)(sp * __cosf(f));
    sQP[r * KPS + d + 64] = (f16)(sp * __sinf(f));
  }
  __syncthreads();

  // Q A-frags into registers: rows wv*32 + mt*16 + lm, k = ks*32 + q*8 + j
  f16x8 qf[2][4];
#pragma unroll
  for (int mt = 0; mt < 2; ++mt)
#pragma unroll
    for (int ks = 0; ks < 4; ++ks)
      qf[mt][ks] = *(const f16x8*)(sQP + (wv * 32 + mt * 16 + lm) * KPS + ks * 32 + q * 8);
  __syncthreads();  // before sQP is reused as P

  f32x4 O[2][4] = {};
  float mrow[2][4], lrow[2][4];
#pragma unroll
  for (int i = 0; i < 2; ++i)
#pragma unroll
    for (int g = 0; g < 4; ++g) { mrow[i][g] = -INFINITY; lrow[i][g] = 0.f; }
  f16* sP = sQP + wv * 32 * VTS;  // wave-private

  for (int kt = 0; kt < 16; ++kt) {
    // ---- stage polar K tile + V^T tile ----
#pragma unroll 2
    for (int it = 0; it < 16; ++it) {
      int idx = tid + it * 256;       // 0..4095
      int r = idx >> 6, d = idx & 63;
      int nk = kt * 64 + r;
      const f16* base = qkv + (tok0 + nk) * EQKV + h * 64 + d;
      float kv = (float)base[1024];
      float sp = softplusf(kv);
      float f = freqs[nk * 64 + d] + fbias[nk * 64 + d];
      sKP[r * KPS + d]      = (f16)(sp * __cosf(f));
      sKP[r * KPS + d + 64] = (f16)(sp * __sinf(f));
      sVT[d * VTS + r] = base[2048];
    }
    __syncthreads();

    // ---- S = QP * KP^T ----
    f32x4 S[2][4] = {};
#pragma unroll
    for (int nt = 0; nt < 4; ++nt) {
      f16x8 kf[4];
#pragma unroll
      for (int ks = 0; ks < 4; ++ks)
        kf[ks] = *(const f16x8*)(sKP + (nt * 16 + lm) * KPS + ks * 32 + q * 8);
#pragma unroll
      for (int mt = 0; mt < 2; ++mt)
#pragma unroll
        for (int ks = 0; ks < 4; ++ks)
          S[mt][nt] = __builtin_amdgcn_mfma_f32_16x16x32_f16(qf[mt][ks], kf[ks], S[mt][nt], 0, 0, 0);
    }

    // ---- online softmax (rows live in 16-lane quad groups) ----
#pragma unroll
    for (int mt = 0; mt < 2; ++mt) {
#pragma unroll
      for (int g = 0; g < 4; ++g) {
        float mx = fmaxf(fmaxf(S[mt][0][g], S[mt][1][g]), fmaxf(S[mt][2][g], S[mt][3][g]));
#pragma unroll
        for (int off = 8; off; off >>= 1) mx = fmaxf(mx, __shfl_xor(mx, off, 64));
        float mn = fmaxf(mrow[mt][g], mx);
        float alpha = __expf(mrow[mt][g] - mn);
        mrow[mt][g] = mn;
        float rs = 0.f;
#pragma unroll
        for (int nt = 0; nt < 4; ++nt) {
          float p = __expf(S[mt][nt][g] - mn);
          S[mt][nt][g] = p;
          rs += p;
        }
#pragma unroll
        for (int off = 8; off; off >>= 1) rs += __shfl_xor(rs, off, 64);
        lrow[mt][g] = lrow[mt][g] * alpha + rs;
#pragma unroll
        for (int nt = 0; nt < 4; ++nt) O[mt][nt][g] *= alpha;
      }
    }

    // ---- P to wave-private LDS (C-layout -> A-layout transform) ----
#pragma unroll
    for (int mt = 0; mt < 2; ++mt)
#pragma unroll
      for (int nt = 0; nt < 4; ++nt)
#pragma unroll
        for (int g = 0; g < 4; ++g)
          sP[(mt * 16 + q * 4 + g) * VTS + nt * 16 + lm] = (f16)S[mt][nt][g];

    // ---- O += P * V ----
    f16x8 pf[2][2];
#pragma unroll
    for (int mt = 0; mt < 2; ++mt)
#pragma unroll
      for (int ks = 0; ks < 2; ++ks)
        pf[mt][ks] = *(const f16x8*)(sP + (mt * 16 + lm) * VTS + ks * 32 + q * 8);
#pragma unroll
    for (int nto = 0; nto < 4; ++nto) {
      f16x8 vf0 = *(const f16x8*)(sVT + (nto * 16 + lm) * VTS + 0 * 32 + q * 8);
      f16x8 vf1 = *(const f16x8*)(sVT + (nto * 16 + lm) * VTS + 1 * 32 + q * 8);
#pragma unroll
      for (int mt = 0; mt < 2; ++mt) {
        O[mt][nto] = __builtin_amdgcn_mfma_f32_16x16x32_f16(pf[mt][0], vf0, O[mt][nto], 0, 0, 0);
        O[mt][nto] = __builtin_amdgcn_mfma_f32_16x16x32_f16(pf[mt][1], vf1, O[mt][nto], 0, 0, 0);
      }
    }
    __syncthreads();
  }

  // ---- epilogue: O / l -> attout[token][h*64 + col] ----
#pragma unroll
  for (int mt = 0; mt < 2; ++mt) {
#pragma unroll
    for (int g = 0; g < 4; ++g) {
      int rloc = wv * 32 + mt * 16 + q * 4 + g;
      size_t token = tok0 + qt * 128 + rloc;
      float inv = 1.f / lrow[mt][g];
#pragma unroll
      for (int nto = 0; nto < 4; ++nto)
        attout[token * (size_t)(Hh * DH) + h * 64 + nto * 16 + lm] =
            (f16)(O[mt][nto][g] * inv);
    }
  }
}

// ---------------- launch ----------------
extern "C" void kernel_launch(void* const* d_in, const int* in_sizes, int n_in,
                              void* d_out, int out_size, void* d_ws, size_t ws_size,
                              hipStream_t stream) {
  const float* x     = (const float*)d_in[0];
  const float* freqs = (const float*)d_in[1];
  const float* fbias = (const float*)d_in[2];
  const float* gamma = (const float*)d_in[3];
  const float* beta  = (const float*)d_in[4];
  const float* w_qk  = (const float*)d_in[5];
  const float* w_v   = (const float*)d_in[6];
  const float* w_out = (const float*)d_in[7];
  const float* b_out = (const float*)d_in[8];
  float* out = (float*)d_out;

  const size_t T = (size_t)Bb * Nn;  // 8192 tokens
  f16* WqkvT = (f16*)d_ws;                        // [3072][1024]
  f16* WoutT = WqkvT + (size_t)EQKV * DIM;        // [1024][1024]
  f16* Xn    = WoutT + (size_t)DIM * DIM;         // [8192][1024]
  f16* QKV   = Xn + T * DIM;                      // [8192][3072]
  f16* AttO  = QKV + T * EQKV;                    // [8192][1024]

  // weights -> fp16 transposed (B^T layout for gemm_bt)
  transpose_cvt<<<dim3(2048 / 32, 1024 / 32), 256, 0, stream>>>(w_qk, WqkvT, DIM, 2048);
  transpose_cvt<<<dim3(1024 / 32, 1024 / 32), 256, 0, stream>>>(w_v, WqkvT + (size_t)2048 * DIM, DIM, 1024);
  transpose_cvt<<<dim3(1024 / 32, 1024 / 32), 256, 0, stream>>>(w_out, WoutT, DIM, DIM);

  ln_kernel<<<(int)T, 256, 0, stream>>>(x, gamma, beta, Xn);

  gemm_bt<false><<<(int)(T / 128) * (EQKV / 128), 256, 0, stream>>>(
      Xn, WqkvT, (void*)QKV, nullptr, (int)T, DIM, EQKV);

  attn_kernel<<<Bb * Hh * (Nn / 128), 256, 0, stream>>>(QKV, freqs, fbias, AttO);

  gemm_bt<true><<<(int)(T / 128) * (DIM / 128), 256, 0, stream>>>(
      AttO, WoutT, (void*)out, b_out, (int)T, DIM, DIM);
}

// Round 2
// 431.540 us; speedup vs baseline: 1.4275x; 1.4275x over previous
//
#include <hip/hip_runtime.h>
#include <cmath>

using f16   = _Float16;
using f16x4 = __attribute__((ext_vector_type(4))) _Float16;
using f16x8 = __attribute__((ext_vector_type(8))) _Float16;
using f32x4 = __attribute__((ext_vector_type(4))) float;

#define DEV __device__ __forceinline__

// ---- constants ----
constexpr int Bb  = 8;
constexpr int Nn  = 1024;
constexpr int DIM = 1024;
constexpr int Hh  = 16;
constexpr int DH  = 64;
constexpr int EQKV = 3072;   // q(1024) | k(1024) | v(1024)

DEV void async16(const f16* g, f16* l) {
  __builtin_amdgcn_global_load_lds(
      (const __attribute__((address_space(1))) void*)g,
      (__attribute__((address_space(3))) void*)l, 16, 0, 0);
}

DEV float softplusf(float x) {
  // stable: max(x,0) + log1p(exp(-|x|))
  return fmaxf(x, 0.f) + log1pf(__expf(-fabsf(x)));
}

// ---------------- transpose + fp32->fp16 convert: dst[c][r] = src[r][c] ----------------
__global__ __launch_bounds__(256) void transpose_cvt(const float* __restrict__ src,
                                                     f16* __restrict__ dst,
                                                     int rows, int cols) {
  __shared__ float tile[32][33];
  int t = threadIdx.x, tx = t & 31, ty = t >> 5;
  int c0 = blockIdx.x * 32, r0 = blockIdx.y * 32;
#pragma unroll
  for (int j = 0; j < 32; j += 8)
    tile[ty + j][tx] = src[(size_t)(r0 + ty + j) * cols + c0 + tx];
  __syncthreads();
#pragma unroll
  for (int j = 0; j < 32; j += 8)
    dst[(size_t)(c0 + ty + j) * rows + r0 + tx] = (f16)tile[tx][ty + j];
}

// ---------------- LayerNorm (fp32 in, fp16 out), one block per token row ----------------
__global__ __launch_bounds__(256) void ln_kernel(const float* __restrict__ x,
                                                 const float* __restrict__ gamma,
                                                 const float* __restrict__ beta,
                                                 f16* __restrict__ xn) {
  int row = blockIdx.x;
  int t = threadIdx.x;
  const float4* xr = (const float4*)(x + (size_t)row * DIM);
  float4 v = xr[t];
  float s  = v.x + v.y + v.z + v.w;
  float s2 = v.x * v.x + v.y * v.y + v.z * v.z + v.w * v.w;
#pragma unroll
  for (int off = 32; off; off >>= 1) {
    s  += __shfl_xor(s,  off, 64);
    s2 += __shfl_xor(s2, off, 64);
  }
  __shared__ float red[8];
  int wv = t >> 6, lane = t & 63;
  if (lane == 0) { red[wv] = s; red[4 + wv] = s2; }
  __syncthreads();
  s  = red[0] + red[1] + red[2] + red[3];
  s2 = red[4] + red[5] + red[6] + red[7];
  float mu  = s * (1.f / DIM);
  float var = s2 * (1.f / DIM) - mu * mu;
  float rs  = rsqrtf(var + 1e-5f);
  float4 g = ((const float4*)gamma)[t];
  float4 bb = ((const float4*)beta)[t];
  f16x4 o;
  o[0] = (f16)((v.x - mu) * rs * g.x + bb.x);
  o[1] = (f16)((v.y - mu) * rs * g.y + bb.y);
  o[2] = (f16)((v.z - mu) * rs * g.z + bb.z);
  o[3] = (f16)((v.w - mu) * rs * g.w + bb.w);
  ((f16x4*)(xn + (size_t)row * DIM))[t] = o;
}

// ---------------- m97-style GEMM: C[M,E] = A[M,K] * Bt[E,K]^T ----------------
template <bool FP32OUT>
__global__ __launch_bounds__(256) void gemm_bt(const f16* __restrict__ A,
                                               const f16* __restrict__ Bt,
                                               void* __restrict__ Cv,
                                               const float* __restrict__ bias,
                                               int M, int K, int E) {
  __shared__ f16 lA[128 * 32];
  __shared__ f16 lB[128 * 32];
  int tid  = threadIdx.x;
  int lane = tid & 63;
  int wv   = __builtin_amdgcn_readfirstlane(tid >> 6);
  int nbe  = E >> 7;
  int bm = blockIdx.x / nbe, be = blockIdx.x % nbe;
  size_t m0 = (size_t)bm * 128, e0 = (size_t)be * 128;
  int wm = (wv & 1) * 64, we = (wv >> 1) * 64;
  int lm = lane & 15, q = lane >> 4;

  f32x4 acc[4][4] = {};

  int row_s[2], cg_s[2];
#pragma unroll
  for (int r = 0; r < 2; ++r) {
    int s = r * 256 + tid;
    row_s[r] = s >> 2;
    cg_s[r]  = (s & 3) ^ ((row_s[r] >> 1) & 3);
  }
  const f16* pa[4];
  const f16* pb[4];
#pragma unroll
  for (int i = 0; i < 4; ++i) {
    int ra = wm + i * 16 + lm;
    pa[i] = lA + ra * 32 + (q ^ ((ra >> 1) & 3)) * 8;
    int rb = we + i * 16 + lm;
    pb[i] = lB + rb * 32 + (q ^ ((rb >> 1) & 3)) * 8;
  }

  for (int k0 = 0; k0 < K; k0 += 32) {
#pragma unroll
    for (int r = 0; r < 2; ++r) {
      const f16* ga = A  + (m0 + row_s[r]) * K + k0 + cg_s[r] * 8;
      const f16* gb = Bt + (e0 + row_s[r]) * K + k0 + cg_s[r] * 8;
      f16* la = lA + (r * 256 + wv * 64) * 8;
      f16* lb = lB + (r * 256 + wv * 64) * 8;
      async16(ga, la);
      async16(gb, lb);
    }
    __syncthreads();
    f16x8 af[4], bf[4];
#pragma unroll
    for (int i = 0; i < 4; ++i) {
      af[i] = *(const f16x8*)pa[i];
      bf[i] = *(const f16x8*)pb[i];
    }
#pragma unroll
    for (int i = 0; i < 4; ++i)
#pragma unroll
      for (int j = 0; j < 4; ++j)
        acc[i][j] = __builtin_amdgcn_mfma_f32_16x16x32_f16(af[i], bf[j], acc[i][j], 0, 0, 0);
    __syncthreads();
  }

#pragma unroll
  for (int i = 0; i < 4; ++i) {
    size_t mbase = m0 + wm + i * 16 + q * 4;
#pragma unroll
    for (int j = 0; j < 4; ++j) {
      size_t e = e0 + we + j * 16 + lm;
#pragma unroll
      for (int g = 0; g < 4; ++g) {
        float val = acc[i][j][g];
        if (FP32OUT)
          ((float*)Cv)[(mbase + g) * (size_t)E + e] = val + bias[e];
        else
          ((f16*)Cv)[(mbase + g) * (size_t)E + e] = (f16)val;
      }
    }
  }
}

// ---------------- polar precompute ----------------
// One pass: Qp[bh,n,128] (scale folded), Kp[bh,n,128], Vt[bh,d,n] (transposed).
// Block = (bh, 64-token chunk). Eliminates the 8x-redundant transcendentals.
__global__ __launch_bounds__(256) void polar_kernel(const f16* __restrict__ qkv,
                                                    const float* __restrict__ freqs,
                                                    const float* __restrict__ fbias,
                                                    f16* __restrict__ Qp,
                                                    f16* __restrict__ Kp,
                                                    f16* __restrict__ Vt) {
  __shared__ f16 vt[64 * 66];  // stride 66 halfs = 33 dwords -> 2-way max (free)
  int tid = threadIdx.x;
  int bx = blockIdx.x;
  int nt = bx & 15, bh = bx >> 4;
  int b = bh >> 4, h = bh & 15;
  size_t tok0 = (size_t)b * Nn + nt * 64;
  int n0 = nt * 64;
  constexpr float kScale = 0.125f;  // DH^-0.5 folded into Qp
#pragma unroll 4
  for (int i = 0; i < 16; ++i) {
    int e = tid + i * 256;  // 0..4095
    int nl = e >> 6, d = e & 63;
    size_t src = (tok0 + nl) * EQKV + h * 64 + d;
    float qv = (float)qkv[src];
    float kv = (float)qkv[src + 1024];
    int fidx = (n0 + nl) * 64 + d;
    float fq = freqs[fidx];
    float fk = fq + fbias[fidx];
    float spq = softplusf(qv) * kScale;
    float spk = softplusf(kv);
    float sq, cq, sk, ck;
    __sincosf(fq, &sq, &cq);
    __sincosf(fk, &sk, &ck);
    size_t dst = ((size_t)bh * Nn + n0 + nl) * 128 + d;
    Qp[dst]      = (f16)(spq * cq);
    Qp[dst + 64] = (f16)(spq * sq);
    Kp[dst]      = (f16)(spk * ck);
    Kp[dst + 64] = (f16)(spk * sk);
    vt[d * 66 + nl] = qkv[src + 2048];
  }
  __syncthreads();
#pragma unroll 4
  for (int i = 0; i < 16; ++i) {
    int e = tid + i * 256;
    int d = e >> 6, nl = e & 63;
    Vt[((size_t)bh * 64 + d) * Nn + n0 + nl] = vt[d * 66 + nl];
  }
}

// ---------------- flash attention (pure MFMA, precomputed polar inputs) ----------------
// block = (bh, 128-row q-tile), 4 waves (32 q-rows each); K-tile = 64 keys.
// All staging via global_load_lds(16B) with XOR chunk swizzle:
//   LDS chunk c of row r holds global chunk c ^ (r & mask) -> frag reads conflict-free.
__global__ __launch_bounds__(256) void attn_kernel(const f16* __restrict__ Qp,
                                                   const f16* __restrict__ Kp,
                                                   const f16* __restrict__ Vt,
                                                   f16* __restrict__ attout) {
  __shared__ f16 sK[64 * 128];    // 16 KB, 64 keys x 128 d2
  __shared__ f16 sV[64 * 64];     // 8 KB,  64 d x 64 keys (from Vt)
  __shared__ f16 sQP[128 * 128];  // 32 KB, Q staging; then per-wave P (32x64, swizzled)

  int tid = threadIdx.x, lane = tid & 63;
  int wv = __builtin_amdgcn_readfirstlane(tid >> 6);
  int lm = lane & 15, q = lane >> 4;
  int bx = blockIdx.x;
  int qt = bx & 7, bh = bx >> 3;  // qt fastest -> 8 blocks of same bh hit L2/L3 together
  const f16* Qbase = Qp + ((size_t)bh * Nn + qt * 128) * 128;
  const f16* Kbase = Kp + (size_t)bh * Nn * 128;
  const f16* Vbase = Vt + (size_t)bh * 64 * Nn;

  // ---- stage Q tile (128 x 128 halfs = 2048 16B slots) ----
#pragma unroll
  for (int i = 0; i < 8; ++i) {
    int s = i * 256 + tid;
    int r = s >> 4, c = s & 15;
    int g = c ^ (r & 15);
    async16(Qbase + (size_t)r * 128 + g * 8, sQP + (i * 256 + wv * 64) * 8);
  }
  __syncthreads();

  // Q A-frags -> registers: row = wv*32 + mt*16 + lm, k-chunk = ks*4 + q
  f16x8 qf[2][4];
#pragma unroll
  for (int mt = 0; mt < 2; ++mt)
#pragma unroll
    for (int ks = 0; ks < 4; ++ks) {
      int row = wv * 32 + mt * 16 + lm;
      qf[mt][ks] = *(const f16x8*)(sQP + row * 128 + (((ks * 4 + q) ^ (row & 15)) * 8));
    }
  __syncthreads();  // all Q reads done before sQP is reused as P

  f32x4 O[2][4] = {};
  float mrow[2][4], lrow[2][4];
#pragma unroll
  for (int i = 0; i < 2; ++i)
#pragma unroll
    for (int g = 0; g < 4; ++g) { mrow[i][g] = -INFINITY; lrow[i][g] = 0.f; }
  f16* sP = sQP + wv * 2048;  // wave-private 32 x 64 halfs

  for (int kt = 0; kt < 16; ++kt) {
    // ---- stage K tile (1024 slots) + V tile (512 slots) ----
#pragma unroll
    for (int i = 0; i < 4; ++i) {
      int s = i * 256 + tid;
      int r = s >> 4, c = s & 15;
      int g = c ^ (r & 15);
      async16(Kbase + (size_t)(kt * 64 + r) * 128 + g * 8, sK + (i * 256 + wv * 64) * 8);
    }
#pragma unroll
    for (int i = 0; i < 2; ++i) {
      int s = i * 256 + tid;
      int r = s >> 3, c = s & 7;
      int g = c ^ (r & 7);
      async16(Vbase + (size_t)r * Nn + kt * 64 + g * 8, sV + (i * 256 + wv * 64) * 8);
    }
    __syncthreads();

    // ---- S = Qp * Kp^T (rows: wave's 32 q; cols: 64 keys) ----
    f32x4 S[2][4] = {};
#pragma unroll
    for (int nt = 0; nt < 4; ++nt) {
      f16x8 kf[4];
#pragma unroll
      for (int ks = 0; ks < 4; ++ks)
        kf[ks] = *(const f16x8*)(sK + (nt * 16 + lm) * 128 + (((ks * 4 + q) ^ lm) * 8));
#pragma unroll
      for (int mt = 0; mt < 2; ++mt)
#pragma unroll
        for (int ks = 0; ks < 4; ++ks)
          S[mt][nt] = __builtin_amdgcn_mfma_f32_16x16x32_f16(qf[mt][ks], kf[ks], S[mt][nt], 0, 0, 0);
    }

    // ---- online softmax (row = 16-lane group within quad q) ----
#pragma unroll
    for (int mt = 0; mt < 2; ++mt) {
#pragma unroll
      for (int g = 0; g < 4; ++g) {
        float mx = fmaxf(fmaxf(S[mt][0][g], S[mt][1][g]), fmaxf(S[mt][2][g], S[mt][3][g]));
#pragma unroll
        for (int off = 8; off; off >>= 1) mx = fmaxf(mx, __shfl_xor(mx, off, 64));
        float mn = fmaxf(mrow[mt][g], mx);
        float alpha = __expf(mrow[mt][g] - mn);
        mrow[mt][g] = mn;
        float rs = 0.f;
#pragma unroll
        for (int nt = 0; nt < 4; ++nt) {
          float p = __expf(S[mt][nt][g] - mn);
          S[mt][nt][g] = p;
          rs += p;
        }
#pragma unroll
        for (int off = 8; off; off >>= 1) rs += __shfl_xor(rs, off, 64);
        lrow[mt][g] = lrow[mt][g] * alpha + rs;
#pragma unroll
        for (int nt = 0; nt < 4; ++nt) O[mt][nt][g] *= alpha;
      }
    }

    // ---- P -> wave-private swizzled LDS (C-layout -> A-layout) ----
#pragma unroll
    for (int mt = 0; mt < 2; ++mt)
#pragma unroll
      for (int nt = 0; nt < 4; ++nt)
#pragma unroll
        for (int g = 0; g < 4; ++g) {
          int rl = mt * 16 + q * 4 + g;
          int col = nt * 16 + lm;
          int ch = (col >> 3) ^ (rl & 7);
          sP[rl * 64 + ch * 8 + (col & 7)] = (f16)S[mt][nt][g];
        }

    // ---- O += P * V ----
    f16x8 pf[2][2];
#pragma unroll
    for (int mt = 0; mt < 2; ++mt)
#pragma unroll
      for (int ks = 0; ks < 2; ++ks) {
        int row = mt * 16 + lm;
        pf[mt][ks] = *(const f16x8*)(sP + row * 64 + (((ks * 4 + q) ^ (lm & 7)) * 8));
      }
#pragma unroll
    for (int nto = 0; nto < 4; ++nto) {
      int row = nto * 16 + lm;
      f16x8 vf0 = *(const f16x8*)(sV + row * 64 + (((0 * 4 + q) ^ (lm & 7)) * 8));
      f16x8 vf1 = *(const f16x8*)(sV + row * 64 + (((1 * 4 + q) ^ (lm & 7)) * 8));
#pragma unroll
      for (int mt = 0; mt < 2; ++mt) {
        O[mt][nto] = __builtin_amdgcn_mfma_f32_16x16x32_f16(pf[mt][0], vf0, O[mt][nto], 0, 0, 0);
        O[mt][nto] = __builtin_amdgcn_mfma_f32_16x16x32_f16(pf[mt][1], vf1, O[mt][nto], 0, 0, 0);
      }
    }
    __syncthreads();  // before restaging sK/sV
  }

  // ---- epilogue ----
  int b = bh >> 4, h = bh & 15;
  size_t tok0 = (size_t)b * Nn + qt * 128;
#pragma unroll
  for (int mt = 0; mt < 2; ++mt) {
#pragma unroll
    for (int g = 0; g < 4; ++g) {
      int rloc = wv * 32 + mt * 16 + q * 4 + g;
      size_t token = tok0 + rloc;
      float inv = 1.f / lrow[mt][g];
#pragma unroll
      for (int nto = 0; nto < 4; ++nto)
        attout[token * (size_t)(Hh * DH) + h * 64 + nto * 16 + lm] =
            (f16)(O[mt][nto][g] * inv);
    }
  }
}

// ---------------- launch ----------------
extern "C" void kernel_launch(void* const* d_in, const int* in_sizes, int n_in,
                              void* d_out, int out_size, void* d_ws, size_t ws_size,
                              hipStream_t stream) {
  const float* x     = (const float*)d_in[0];
  const float* freqs = (const float*)d_in[1];
  const float* fbias = (const float*)d_in[2];
  const float* gamma = (const float*)d_in[3];
  const float* beta  = (const float*)d_in[4];
  const float* w_qk  = (const float*)d_in[5];
  const float* w_v   = (const float*)d_in[6];
  const float* w_out = (const float*)d_in[7];
  const float* b_out = (const float*)d_in[8];
  float* out = (float*)d_out;

  const size_t T = (size_t)Bb * Nn;  // 8192 tokens
  f16* WqkvT = (f16*)d_ws;                        // [3072][1024]
  f16* WoutT = WqkvT + (size_t)EQKV * DIM;        // [1024][1024]
  f16* Xn    = WoutT + (size_t)DIM * DIM;         // [8192][1024]
  f16* QKV   = Xn + T * DIM;                      // [8192][3072]
  f16* AttO  = QKV + T * EQKV;                    // [8192][1024]
  f16* Qp    = AttO + T * DIM;                    // [128][1024][128]
  f16* Kp    = Qp + (size_t)128 * Nn * 128;       // [128][1024][128]
  f16* Vt    = Kp + (size_t)128 * Nn * 128;       // [128][64][1024]

  transpose_cvt<<<dim3(2048 / 32, 1024 / 32), 256, 0, stream>>>(w_qk, WqkvT, DIM, 2048);
  transpose_cvt<<<dim3(1024 / 32, 1024 / 32), 256, 0, stream>>>(w_v, WqkvT + (size_t)2048 * DIM, DIM, 1024);
  transpose_cvt<<<dim3(1024 / 32, 1024 / 32), 256, 0, stream>>>(w_out, WoutT, DIM, DIM);

  ln_kernel<<<(int)T, 256, 0, stream>>>(x, gamma, beta, Xn);

  gemm_bt<false><<<(int)(T / 128) * (EQKV / 128), 256, 0, stream>>>(
      Xn, WqkvT, (void*)QKV, nullptr, (int)T, DIM, EQKV);

  polar_kernel<<<Bb * Hh * (Nn / 64), 256, 0, stream>>>(QKV, freqs, fbias, Qp, Kp, Vt);

  attn_kernel<<<Bb * Hh * (Nn / 128), 256, 0, stream>>>(Qp, Kp, Vt, AttO);

  gemm_bt<true><<<(int)(T / 128) * (DIM / 128), 256, 0, stream>>>(
      AttO, WoutT, (void*)out, b_out, (int)T, DIM, DIM);
}

// Round 3
// 412.047 us; speedup vs baseline: 1.4951x; 1.0473x over previous
//
#include <hip/hip_runtime.h>
#include <cmath>

using f16   = _Float16;
using f16x4 = __attribute__((ext_vector_type(4))) _Float16;
using f16x8 = __attribute__((ext_vector_type(8))) _Float16;
using f32x4 = __attribute__((ext_vector_type(4))) float;

#define DEV __device__ __forceinline__

// ---- constants ----
constexpr int Bb  = 8;
constexpr int Nn  = 1024;
constexpr int DIM = 1024;
constexpr int Hh  = 16;
constexpr int DH  = 64;
constexpr int EQKV = 3072;   // q(1024) | k(1024) | v(1024)

DEV void async16(const f16* g, f16* l) {
  __builtin_amdgcn_global_load_lds(
      (const __attribute__((address_space(1))) void*)g,
      (__attribute__((address_space(3))) void*)l, 16, 0, 0);
}

DEV float softplusf(float x) {
  // stable: max(x,0) + log1p(exp(-|x|))
  return fmaxf(x, 0.f) + log1pf(__expf(-fabsf(x)));
}

// ---------------- transpose + fp32->fp16 convert: dst[c][r] = src[r][c] ----------------
__global__ __launch_bounds__(256) void transpose_cvt(const float* __restrict__ src,
                                                     f16* __restrict__ dst,
                                                     int rows, int cols) {
  __shared__ float tile[32][33];
  int t = threadIdx.x, tx = t & 31, ty = t >> 5;
  int c0 = blockIdx.x * 32, r0 = blockIdx.y * 32;
#pragma unroll
  for (int j = 0; j < 32; j += 8)
    tile[ty + j][tx] = src[(size_t)(r0 + ty + j) * cols + c0 + tx];
  __syncthreads();
#pragma unroll
  for (int j = 0; j < 32; j += 8)
    dst[(size_t)(c0 + ty + j) * rows + r0 + tx] = (f16)tile[tx][ty + j];
}

// ---------------- LayerNorm (fp32 in, fp16 out), one block per token row ----------------
__global__ __launch_bounds__(256) void ln_kernel(const float* __restrict__ x,
                                                 const float* __restrict__ gamma,
                                                 const float* __restrict__ beta,
                                                 f16* __restrict__ xn) {
  int row = blockIdx.x;
  int t = threadIdx.x;
  const float4* xr = (const float4*)(x + (size_t)row * DIM);
  float4 v = xr[t];
  float s  = v.x + v.y + v.z + v.w;
  float s2 = v.x * v.x + v.y * v.y + v.z * v.z + v.w * v.w;
#pragma unroll
  for (int off = 32; off; off >>= 1) {
    s  += __shfl_xor(s,  off, 64);
    s2 += __shfl_xor(s2, off, 64);
  }
  __shared__ float red[8];
  int wv = t >> 6, lane = t & 63;
  if (lane == 0) { red[wv] = s; red[4 + wv] = s2; }
  __syncthreads();
  s  = red[0] + red[1] + red[2] + red[3];
  s2 = red[4] + red[5] + red[6] + red[7];
  float mu  = s * (1.f / DIM);
  float var = s2 * (1.f / DIM) - mu * mu;
  float rs  = rsqrtf(var + 1e-5f);
  float4 g = ((const float4*)gamma)[t];
  float4 bb = ((const float4*)beta)[t];
  f16x4 o;
  o[0] = (f16)((v.x - mu) * rs * g.x + bb.x);
  o[1] = (f16)((v.y - mu) * rs * g.y + bb.y);
  o[2] = (f16)((v.z - mu) * rs * g.z + bb.z);
  o[3] = (f16)((v.w - mu) * rs * g.w + bb.w);
  ((f16x4*)(xn + (size_t)row * DIM))[t] = o;
}

// ---------------- m97-style GEMM: C[M,E] = A[M,K] * Bt[E,K]^T ----------------
template <bool FP32OUT>
__global__ __launch_bounds__(256) void gemm_bt(const f16* __restrict__ A,
                                               const f16* __restrict__ Bt,
                                               void* __restrict__ Cv,
                                               const float* __restrict__ bias,
                                               int M, int K, int E) {
  __shared__ f16 lA[128 * 32];
  __shared__ f16 lB[128 * 32];
  int tid  = threadIdx.x;
  int lane = tid & 63;
  int wv   = __builtin_amdgcn_readfirstlane(tid >> 6);
  int nbe  = E >> 7;
  int bm = blockIdx.x / nbe, be = blockIdx.x % nbe;
  size_t m0 = (size_t)bm * 128, e0 = (size_t)be * 128;
  int wm = (wv & 1) * 64, we = (wv >> 1) * 64;
  int lm = lane & 15, q = lane >> 4;

  f32x4 acc[4][4] = {};

  int row_s[2], cg_s[2];
#pragma unroll
  for (int r = 0; r < 2; ++r) {
    int s = r * 256 + tid;
    row_s[r] = s >> 2;
    cg_s[r]  = (s & 3) ^ ((row_s[r] >> 1) & 3);
  }
  const f16* pa[4];
  const f16* pb[4];
#pragma unroll
  for (int i = 0; i < 4; ++i) {
    int ra = wm + i * 16 + lm;
    pa[i] = lA + ra * 32 + (q ^ ((ra >> 1) & 3)) * 8;
    int rb = we + i * 16 + lm;
    pb[i] = lB + rb * 32 + (q ^ ((rb >> 1) & 3)) * 8;
  }

  for (int k0 = 0; k0 < K; k0 += 32) {
#pragma unroll
    for (int r = 0; r < 2; ++r) {
      const f16* ga = A  + (m0 + row_s[r]) * K + k0 + cg_s[r] * 8;
      const f16* gb = Bt + (e0 + row_s[r]) * K + k0 + cg_s[r] * 8;
      f16* la = lA + (r * 256 + wv * 64) * 8;
      f16* lb = lB + (r * 256 + wv * 64) * 8;
      async16(ga, la);
      async16(gb, lb);
    }
    __syncthreads();
    f16x8 af[4], bf[4];
#pragma unroll
    for (int i = 0; i < 4; ++i) {
      af[i] = *(const f16x8*)pa[i];
      bf[i] = *(const f16x8*)pb[i];
    }
#pragma unroll
    for (int i = 0; i < 4; ++i)
#pragma unroll
      for (int j = 0; j < 4; ++j)
        acc[i][j] = __builtin_amdgcn_mfma_f32_16x16x32_f16(af[i], bf[j], acc[i][j], 0, 0, 0);
    __syncthreads();
  }

#pragma unroll
  for (int i = 0; i < 4; ++i) {
    size_t mbase = m0 + wm + i * 16 + q * 4;
#pragma unroll
    for (int j = 0; j < 4; ++j) {
      size_t e = e0 + we + j * 16 + lm;
#pragma unroll
      for (int g = 0; g < 4; ++g) {
        float val = acc[i][j][g];
        if (FP32OUT)
          ((float*)Cv)[(mbase + g) * (size_t)E + e] = val + bias[e];
        else
          ((f16*)Cv)[(mbase + g) * (size_t)E + e] = (f16)val;
      }
    }
  }
}

// ---------------- polar precompute ----------------
__global__ __launch_bounds__(256) void polar_kernel(const f16* __restrict__ qkv,
                                                    const float* __restrict__ freqs,
                                                    const float* __restrict__ fbias,
                                                    f16* __restrict__ Qp,
                                                    f16* __restrict__ Kp,
                                                    f16* __restrict__ Vt) {
  __shared__ f16 vt[64 * 66];
  int tid = threadIdx.x;
  int bx = blockIdx.x;
  int nt = bx & 15, bh = bx >> 4;
  int b = bh >> 4, h = bh & 15;
  size_t tok0 = (size_t)b * Nn + nt * 64;
  int n0 = nt * 64;
  constexpr float kScale = 0.125f;  // DH^-0.5 folded into Qp
#pragma unroll 4
  for (int i = 0; i < 16; ++i) {
    int e = tid + i * 256;
    int nl = e >> 6, d = e & 63;
    size_t src = (tok0 + nl) * EQKV + h * 64 + d;
    float qv = (float)qkv[src];
    float kv = (float)qkv[src + 1024];
    int fidx = (n0 + nl) * 64 + d;
    float fq = freqs[fidx];
    float fk = fq + fbias[fidx];
    float spq = softplusf(qv) * kScale;
    float spk = softplusf(kv);
    float sq, cq, sk, ck;
    __sincosf(fq, &sq, &cq);
    __sincosf(fk, &sk, &ck);
    size_t dst = ((size_t)bh * Nn + n0 + nl) * 128 + d;
    Qp[dst]      = (f16)(spq * cq);
    Qp[dst + 64] = (f16)(spq * sq);
    Kp[dst]      = (f16)(spk * ck);
    Kp[dst + 64] = (f16)(spk * sk);
    vt[d * 66 + nl] = qkv[src + 2048];
  }
  __syncthreads();
#pragma unroll 4
  for (int i = 0; i < 16; ++i) {
    int e = tid + i * 256;
    int d = e >> 6, nl = e & 63;
    Vt[((size_t)bh * 64 + d) * Nn + n0 + nl] = vt[d * 66 + nl];
  }
}

// ---------------- flash attention: pipelined (1 barrier/iter, K/V double-buffered) ----------------
// block = (bh, 128-row q-tile), 4 waves; K-tile 64.  XCD swizzle: all 8 qt-blocks of a
// head share bx%8 -> same XCD -> K/V L2-resident.  Prefetch tile kt+1 right after the
// loop-top barrier; DMA overlaps the whole compute of tile kt.
// LDS layout (halfs): K0[0,8192) V0[8192,12288) P[12288,20480) K1[20480,28672) V1[28672,32768)
// Q staged through [P|K1) = [12288,28672) before the loop.
constexpr int SK0 = 0;
constexpr int SV0 = 8192;
constexpr int SP  = 12288;
constexpr int SK1 = 20480;
constexpr int SV1 = 28672;

__global__ __launch_bounds__(256) void attn_kernel(const f16* __restrict__ Qp,
                                                   const f16* __restrict__ Kp,
                                                   const f16* __restrict__ Vt,
                                                   f16* __restrict__ attout) {
  __shared__ f16 smem[32768];  // 64 KB

  int tid = threadIdx.x, lane = tid & 63;
  int wv = __builtin_amdgcn_readfirstlane(tid >> 6);
  int lm = lane & 15, q = lane >> 4;
  int bx = blockIdx.x;
  int bh = (bx & 7) | ((bx >> 6) << 3);  // XCD swizzle: same bh -> same bx%8
  int qt = (bx >> 3) & 7;
  const f16* Qbase = Qp + ((size_t)bh * Nn + qt * 128) * 128;
  const f16* Kbase = Kp + (size_t)bh * Nn * 128;
  const f16* Vbase = Vt + (size_t)bh * 64 * Nn;

  // ---- stage Q tile (128x128 halfs) through [SP..SP+16384) ----
  f16* sQ = smem + SP;
#pragma unroll
  for (int i = 0; i < 8; ++i) {
    int s = i * 256 + tid;
    int r = s >> 4, c = s & 15;
    int g = c ^ (r & 15);
    async16(Qbase + (size_t)r * 128 + g * 8, sQ + (i * 256 + wv * 64) * 8);
  }
  __syncthreads();

  f16x8 qf[2][4];
#pragma unroll
  for (int mt = 0; mt < 2; ++mt)
#pragma unroll
    for (int ks = 0; ks < 4; ++ks) {
      int row = wv * 32 + mt * 16 + lm;
      qf[mt][ks] = *(const f16x8*)(sQ + row * 128 + (((ks * 4 + q) ^ (row & 15)) * 8));
    }

  // ---- prologue: issue tile 0 into K0/V0 (disjoint from Q region, no barrier needed) ----
#pragma unroll
  for (int i = 0; i < 4; ++i) {
    int s = i * 256 + tid;
    int r = s >> 4, c = s & 15;
    int g = c ^ (r & 15);
    async16(Kbase + (size_t)r * 128 + g * 8, smem + SK0 + (i * 256 + wv * 64) * 8);
  }
#pragma unroll
  for (int i = 0; i < 2; ++i) {
    int s = i * 256 + tid;
    int r = s >> 3, c = s & 7;
    int g = c ^ (r & 7);
    async16(Vbase + (size_t)r * Nn + g * 8, smem + SV0 + (i * 256 + wv * 64) * 8);
  }

  f32x4 O[2][4] = {};
  float mrow[2][4], lrow[2][4];
#pragma unroll
  for (int i = 0; i < 2; ++i)
#pragma unroll
    for (int g = 0; g < 4; ++g) { mrow[i][g] = -INFINITY; lrow[i][g] = 0.f; }
  f16* sP = smem + SP + wv * 2048;  // wave-private 32x64

  for (int kt = 0; kt < 16; ++kt) {
    __syncthreads();  // vmcnt(0) drain (prefetch issued a full tile ago) + barrier

    // ---- prefetch tile kt+1 into the other buffer ----
    if (kt < 15) {
      f16* nK = smem + ((kt & 1) ? SK0 : SK1);
      f16* nV = smem + ((kt & 1) ? SV0 : SV1);
#pragma unroll
      for (int i = 0; i < 4; ++i) {
        int s = i * 256 + tid;
        int r = s >> 4, c = s & 15;
        int g = c ^ (r & 15);
        async16(Kbase + (size_t)((kt + 1) * 64 + r) * 128 + g * 8, nK + (i * 256 + wv * 64) * 8);
      }
#pragma unroll
      for (int i = 0; i < 2; ++i) {
        int s = i * 256 + tid;
        int r = s >> 3, c = s & 7;
        int g = c ^ (r & 7);
        async16(Vbase + (size_t)r * Nn + (kt + 1) * 64 + g * 8, nV + (i * 256 + wv * 64) * 8);
      }
    }

    const f16* sK = smem + ((kt & 1) ? SK1 : SK0);
    const f16* sV = smem + ((kt & 1) ? SV1 : SV0);

    // ---- S = Qp * Kp^T ----
    f32x4 S[2][4] = {};
#pragma unroll
    for (int nt = 0; nt < 4; ++nt) {
      f16x8 kf[4];
#pragma unroll
      for (int ks = 0; ks < 4; ++ks)
        kf[ks] = *(const f16x8*)(sK + (nt * 16 + lm) * 128 + (((ks * 4 + q) ^ lm) * 8));
#pragma unroll
      for (int mt = 0; mt < 2; ++mt)
#pragma unroll
        for (int ks = 0; ks < 4; ++ks)
          S[mt][nt] = __builtin_amdgcn_mfma_f32_16x16x32_f16(qf[mt][ks], kf[ks], S[mt][nt], 0, 0, 0);
    }

    // ---- online softmax ----
#pragma unroll
    for (int mt = 0; mt < 2; ++mt) {
#pragma unroll
      for (int g = 0; g < 4; ++g) {
        float mx = fmaxf(fmaxf(S[mt][0][g], S[mt][1][g]), fmaxf(S[mt][2][g], S[mt][3][g]));
#pragma unroll
        for (int off = 8; off; off >>= 1) mx = fmaxf(mx, __shfl_xor(mx, off, 64));
        float mn = fmaxf(mrow[mt][g], mx);
        float alpha = __expf(mrow[mt][g] - mn);
        mrow[mt][g] = mn;
        float rs = 0.f;
#pragma unroll
        for (int nt = 0; nt < 4; ++nt) {
          float p = __expf(S[mt][nt][g] - mn);
          S[mt][nt][g] = p;
          rs += p;
        }
#pragma unroll
        for (int off = 8; off; off >>= 1) rs += __shfl_xor(rs, off, 64);
        lrow[mt][g] = lrow[mt][g] * alpha + rs;
#pragma unroll
        for (int nt = 0; nt < 4; ++nt) O[mt][nt][g] *= alpha;
      }
    }

    // ---- P -> wave-private swizzled LDS (C-layout -> A-layout) ----
#pragma unroll
    for (int mt = 0; mt < 2; ++mt)
#pragma unroll
      for (int nt = 0; nt < 4; ++nt)
#pragma unroll
        for (int g = 0; g < 4; ++g) {
          int rl = mt * 16 + q * 4 + g;
          int col = nt * 16 + lm;
          int ch = (col >> 3) ^ (rl & 7);
          sP[rl * 64 + ch * 8 + (col & 7)] = (f16)S[mt][nt][g];
        }

    // ---- O += P * V ----
    f16x8 pf[2][2];
#pragma unroll
    for (int mt = 0; mt < 2; ++mt)
#pragma unroll
      for (int ks = 0; ks < 2; ++ks) {
        int row = mt * 16 + lm;
        pf[mt][ks] = *(const f16x8*)(sP + row * 64 + (((ks * 4 + q) ^ (lm & 7)) * 8));
      }
#pragma unroll
    for (int nto = 0; nto < 4; ++nto) {
      int row = nto * 16 + lm;
      f16x8 vf0 = *(const f16x8*)(sV + row * 64 + (((0 * 4 + q) ^ (lm & 7)) * 8));
      f16x8 vf1 = *(const f16x8*)(sV + row * 64 + (((1 * 4 + q) ^ (lm & 7)) * 8));
#pragma unroll
      for (int mt = 0; mt < 2; ++mt) {
        O[mt][nto] = __builtin_amdgcn_mfma_f32_16x16x32_f16(pf[mt][0], vf0, O[mt][nto], 0, 0, 0);
        O[mt][nto] = __builtin_amdgcn_mfma_f32_16x16x32_f16(pf[mt][1], vf1, O[mt][nto], 0, 0, 0);
      }
    }
  }

  // ---- epilogue ----
  int b = bh >> 4, h = bh & 15;
  size_t tok0 = (size_t)b * Nn + qt * 128;
#pragma unroll
  for (int mt = 0; mt < 2; ++mt) {
#pragma unroll
    for (int g = 0; g < 4; ++g) {
      int rloc = wv * 32 + mt * 16 + q * 4 + g;
      size_t token = tok0 + rloc;
      float inv = 1.f / lrow[mt][g];
#pragma unroll
      for (int nto = 0; nto < 4; ++nto)
        attout[token * (size_t)(Hh * DH) + h * 64 + nto * 16 + lm] =
            (f16)(O[mt][nto][g] * inv);
    }
  }
}

// ---------------- launch ----------------
extern "C" void kernel_launch(void* const* d_in, const int* in_sizes, int n_in,
                              void* d_out, int out_size, void* d_ws, size_t ws_size,
                              hipStream_t stream) {
  const float* x     = (const float*)d_in[0];
  const float* freqs = (const float*)d_in[1];
  const float* fbias = (const float*)d_in[2];
  const float* gamma = (const float*)d_in[3];
  const float* beta  = (const float*)d_in[4];
  const float* w_qk  = (const float*)d_in[5];
  const float* w_v   = (const float*)d_in[6];
  const float* w_out = (const float*)d_in[7];
  const float* b_out = (const float*)d_in[8];
  float* out = (float*)d_out;

  const size_t T = (size_t)Bb * Nn;  // 8192 tokens
  f16* WqkvT = (f16*)d_ws;                        // [3072][1024]
  f16* WoutT = WqkvT + (size_t)EQKV * DIM;        // [1024][1024]
  f16* Xn    = WoutT + (size_t)DIM * DIM;         // [8192][1024]
  f16* QKV   = Xn + T * DIM;                      // [8192][3072]
  f16* AttO  = QKV + T * EQKV;                    // [8192][1024]
  f16* Qp    = AttO + T * DIM;                    // [128][1024][128]
  f16* Kp    = Qp + (size_t)128 * Nn * 128;       // [128][1024][128]
  f16* Vt    = Kp + (size_t)128 * Nn * 128;       // [128][64][1024]

  transpose_cvt<<<dim3(2048 / 32, 1024 / 32), 256, 0, stream>>>(w_qk, WqkvT, DIM, 2048);
  transpose_cvt<<<dim3(1024 / 32, 1024 / 32), 256, 0, stream>>>(w_v, WqkvT + (size_t)2048 * DIM, DIM, 1024);
  transpose_cvt<<<dim3(1024 / 32, 1024 / 32), 256, 0, stream>>>(w_out, WoutT, DIM, DIM);

  ln_kernel<<<(int)T, 256, 0, stream>>>(x, gamma, beta, Xn);

  gemm_bt<false><<<(int)(T / 128) * (EQKV / 128), 256, 0, stream>>>(
      Xn, WqkvT, (void*)QKV, nullptr, (int)T, DIM, EQKV);

  polar_kernel<<<Bb * Hh * (Nn / 64), 256, 0, stream>>>(QKV, freqs, fbias, Qp, Kp, Vt);

  attn_kernel<<<Bb * Hh * (Nn / 128), 256, 0, stream>>>(Qp, Kp, Vt, AttO);

  gemm_bt<true><<<(int)(T / 128) * (DIM / 128), 256, 0, stream>>>(
      AttO, WoutT, (void*)out, b_out, (int)T, DIM, DIM);
}